// Round 4
// baseline (271.457 us; speedup 1.0000x reference)
//
#include <hip/hip_runtime.h>

// MatrixExpander: out = kron(A, ones(8,8)); B=16,C=16,Ar=Ac=64,mp=8.
// out[b,c, i*8+p, j*8+q] = A[b,c,i,j].  All fp32 in, fp32 out.
//
// Evidence trail (rounds 0-3):
//  - The test's "(bf16, ...)" label is HARD-CODED in both f-string branches
//    -> carries no dtype info. Output is fp32 per the reference (doc path:
//    "else float*").
//  - R1 NaN proves d_in[0] holds full-mantissa fp32 (A).
//  - R3 error identical to R2 -> in_sizes[0]==1,048,576 -> d_in[0] IS A.
//  - R2/R3 bounded err 7.125: bf16-packed words half-filling the fp32
//    buffer = scrambled gaussians. All consistent with fp32-out only.
//
// Kernel: one thread per float4 (4 consecutive out elems); 2 threads share
// one A element (wave reads 32 consecutive floats -> coalesced, L1-served;
// A reused 128x from L2). One dwordx4 store per lane -> 1 KiB/wave stores.
// Pure write-BW-bound: 256 MiB out + 4 MiB in.

__global__ __launch_bounds__(256) void
MatrixExpander_kernel(const float* __restrict__ A,
                      float4* __restrict__ out,
                      int n_vec) {
    int t = blockIdx.x * blockDim.x + threadIdx.x;
    if (t >= n_vec) return;

    // flat fp32 index = 4t over (B*C, 512 rows, 512 cols)
    unsigned s4 = (unsigned)t & 127u;         // float4 slot within row (128/row)
    unsigned j  = s4 >> 1;                    // A column = (4*s4)/8
    unsigned r  = ((unsigned)t >> 7) & 511u;  // output row within (b,c)
    unsigned i  = r >> 3;                     // A row (mp=8)
    unsigned bc = (unsigned)t >> 16;          // fused batch*channel

    unsigned a_idx = (bc << 12) | (i << 6) | j;   // bc*4096 + i*64 + j
    float f = A[a_idx];

    out[t] = make_float4(f, f, f, f);
}

extern "C" void kernel_launch(void* const* d_in, const int* in_sizes, int n_in,
                              void* d_out, int out_size, void* d_ws, size_t ws_size,
                              hipStream_t stream) {
    // A = the 1,048,576-element input (robust to ordering; R3 showed it's d_in[0]).
    const float* A = (const float*)d_in[0];
    for (int k = 0; k < n_in; ++k) {
        if (in_sizes[k] == 1048576) { A = (const float*)d_in[k]; break; }
    }
    float4* out = (float4*)d_out;

    // out_size = 16*16*512*512 = 67,108,864 fp32 -> 16,777,216 float4 stores
    int n_vec = out_size / 4;
    int block = 256;
    int grid  = (n_vec + block - 1) / block;   // 65,536 blocks

    MatrixExpander_kernel<<<grid, block, 0, stream>>>(A, out, n_vec);
}

// Round 6
// 270.533 us; speedup vs baseline: 1.0034x; 1.0034x over previous
//
#include <hip/hip_runtime.h>

// MatrixExpander: out = kron(A, ones(8,8)); B=16,C=16,Ar=Ac=64,mp=8.
// out[b,c, i*8+p, j*8+q] = A[b,c,i,j].  fp32 in, fp32 out (verified R4:
// passed, absmax 0.0).
//
// R4 analysis: dur_us=271 but all top-5 profiled dispatches are 1-GiB
// harness poison-memsets (164 us @ 6.5 TB/s); our kernel is below the
// 162-us profile cutoff, and 164(ws)+41(out)+~55(kernel) ~= 271 -> the
// timed window likely includes re-poisons.
// This round (fixing R5's compile error: nontemporal builtin needs a
// clang-native vector type, not HIP_vector_type):
//  (1) non-temporal 16B stores -- output is write-once (256 MiB == whole
//      LLC; regular stores would thrash it against the poison traffic);
//  (2) 8 stores/thread, block covers 32 KiB contiguous, 16 B/lane
//      per-instruction coalescing kept, 8x fewer waves.

typedef float f32x4 __attribute__((ext_vector_type(4)));

#define K_UNROLL 8

__global__ __launch_bounds__(256) void
MatrixExpander_kernel(const float* __restrict__ A,
                      f32x4* __restrict__ out,
                      int n_vec) {
    int base = blockIdx.x * (256 * K_UNROLL) + threadIdx.x;

#pragma unroll
    for (int k = 0; k < K_UNROLL; ++k) {
        int v = base + k * 256;               // float4 index
        if (v >= n_vec) return;

        // flat fp32 index = 4v over (B*C, 512 rows, 512 cols)
        unsigned s4 = (unsigned)v & 127u;         // float4 slot in row
        unsigned j  = s4 >> 1;                    // A column
        unsigned r  = ((unsigned)v >> 7) & 511u;  // output row in (b,c)
        unsigned i  = r >> 3;                     // A row (mp=8)
        unsigned bc = (unsigned)v >> 16;          // fused batch*channel

        unsigned a_idx = (bc << 12) | (i << 6) | j;
        float f = A[a_idx];

        f32x4 val = {f, f, f, f};
        __builtin_nontemporal_store(val, &out[v]);
    }
}

extern "C" void kernel_launch(void* const* d_in, const int* in_sizes, int n_in,
                              void* d_out, int out_size, void* d_ws, size_t ws_size,
                              hipStream_t stream) {
    // A = the 1,048,576-element input (robust to input ordering).
    const float* A = (const float*)d_in[0];
    for (int k = 0; k < n_in; ++k) {
        if (in_sizes[k] == 1048576) { A = (const float*)d_in[k]; break; }
    }
    f32x4* out = (f32x4*)d_out;

    // out_size = 67,108,864 fp32 -> 16,777,216 float4 -> 8192 blocks
    int n_vec = out_size / 4;
    int per_block = 256 * K_UNROLL;
    int grid = (n_vec + per_block - 1) / per_block;

    MatrixExpander_kernel<<<grid, 256, 0, stream>>>(A, out, n_vec);
}